// Round 3
// baseline (353.749 us; speedup 1.0000x reference)
//
#include <hip/hip_runtime.h>
#include <hip/hip_bf16.h>

// Problem constants (B,T,C,H) = (4, 2048, 1024, 64)
#define B_ 4
#define T_ 2048
#define C_ 1024
#define H_ 64

// ---------------------------------------------------------------------------
// Kernel 1: fused QKV projection.
// x:[B*T, C] fp32, W*:[C, H] fp32 -> q,k,v:[B*T, H] fp32 in workspace.
// q is pre-scaled by C^-0.5 = 1/32 (reference scales q·k by C^-0.5).
// Block = 256 threads (4 waves); each wave handles 4 rows; thread col = lane.
// Register tile: 4 rows x (q,k,v) -> 48 FMAs per 4-c step vs 16 loads.
// ---------------------------------------------------------------------------
__global__ __launch_bounds__(256) void qkv_proj(
    const float* __restrict__ x,
    const float* __restrict__ Wq,
    const float* __restrict__ Wk,
    const float* __restrict__ Wv,
    float* __restrict__ q_out,
    float* __restrict__ k_out,
    float* __restrict__ v_out)
{
    const int lane = threadIdx.x & 63;
    const int wid  = threadIdx.x >> 6;
    const int row0 = blockIdx.x * 16 + wid * 4;   // 4 consecutive rows per wave

    float accq[4] = {0.f, 0.f, 0.f, 0.f};
    float acck[4] = {0.f, 0.f, 0.f, 0.f};
    float accv[4] = {0.f, 0.f, 0.f, 0.f};

    for (int c = 0; c < C_; c += 4) {
        float4 xv[4];
        #pragma unroll
        for (int r = 0; r < 4; ++r)
            xv[r] = *reinterpret_cast<const float4*>(&x[(size_t)(row0 + r) * C_ + c]);

        #pragma unroll
        for (int j = 0; j < 4; ++j) {
            const float wq = Wq[(size_t)(c + j) * H_ + lane];
            const float wk = Wk[(size_t)(c + j) * H_ + lane];
            const float wv = Wv[(size_t)(c + j) * H_ + lane];
            #pragma unroll
            for (int r = 0; r < 4; ++r) {
                const float xs = reinterpret_cast<const float*>(&xv[r])[j];
                accq[r] += xs * wq;
                acck[r] += xs * wk;
                accv[r] += xs * wv;
            }
        }
    }

    const float qscale = 0.03125f;  // 1024^-0.5
    #pragma unroll
    for (int r = 0; r < 4; ++r) {
        const size_t o = (size_t)(row0 + r) * H_ + lane;
        q_out[o] = accq[r] * qscale;
        k_out[o] = acck[r];
        v_out[o] = accv[r];
    }
}

// ---------------------------------------------------------------------------
// Kernel 2: causal flash attention, fp32.
// Grid (T/4, B); block = 256 thr = 4 waves; wave w handles q-row t0+w.
// Per wave: lane = key within a 64-key LDS tile; q row + out accumulator in
// VGPRs (fully unrolled h). Online softmax: wave-max per tile, rescale only
// when the running max grows. LDS tiles padded to 68 floats/row so that
// ds_read_b128 at float offset 68*s + 4*hq spreads 8 lanes/bank-quad (even).
// ---------------------------------------------------------------------------
__global__ __launch_bounds__(256) void attn_fwd(
    const float* __restrict__ q,
    const float* __restrict__ k,
    const float* __restrict__ v,
    float* __restrict__ out)
{
    __shared__ __align__(16) float ks[64][68];
    __shared__ __align__(16) float vs[64][68];

    const int b    = blockIdx.y;
    const int wid  = threadIdx.x >> 6;
    const int lane = threadIdx.x & 63;
    const int t0   = blockIdx.x * 4;
    const int t    = t0 + wid;

    // q row -> 64 VGPRs (pre-scaled by 1/32 in qkv_proj)
    float qv[64];
    {
        const float4* qp = reinterpret_cast<const float4*>(&q[((size_t)b * T_ + t) * H_]);
        #pragma unroll
        for (int i = 0; i < 16; ++i) {
            const float4 tmp = qp[i];
            qv[4*i+0] = tmp.x; qv[4*i+1] = tmp.y;
            qv[4*i+2] = tmp.z; qv[4*i+3] = tmp.w;
        }
    }

    float acc[64];
    #pragma unroll
    for (int i = 0; i < 64; ++i) acc[i] = 0.f;
    float m = -1e30f;
    float l = 0.f;

    const int kbmax = (t0 + 3) >> 6;   // last key tile needed by any row in block
    for (int kb = 0; kb <= kbmax; ++kb) {
        __syncthreads();   // protect previous tile reads
        // Cooperative stage of 64 keys x 64 h for k and v (float4, coalesced).
        #pragma unroll
        for (int rep = 0; rep < 4; ++rep) {
            const int idx = rep * 256 + threadIdx.x;  // 0..1023
            const int s   = idx >> 4;
            const int hq  = idx & 15;
            const size_t g = ((size_t)b * T_ + (size_t)kb * 64 + s) * H_ + hq * 4;
            *reinterpret_cast<float4*>(&ks[s][hq * 4]) = *reinterpret_cast<const float4*>(&k[g]);
            *reinterpret_cast<float4*>(&vs[s][hq * 4]) = *reinterpret_cast<const float4*>(&v[g]);
        }
        __syncthreads();

        if (kb * 64 <= t) {            // wave-uniform: this tile has keys <= t
            const int s = kb * 64 + lane;
            float score = 0.f;
            #pragma unroll
            for (int hq = 0; hq < 16; ++hq) {
                const float4 kk = *reinterpret_cast<const float4*>(&ks[lane][hq * 4]);
                score += qv[4*hq+0] * kk.x + qv[4*hq+1] * kk.y
                       + qv[4*hq+2] * kk.z + qv[4*hq+3] * kk.w;
            }
            if (s > t) score = -1e30f;  // causal mask

            // wave max of this tile's scores
            float bm = score;
            #pragma unroll
            for (int off = 32; off > 0; off >>= 1)
                bm = fmaxf(bm, __shfl_xor(bm, off));

            if (bm > m) {               // rescale only when running max grows
                const float corr = __expf(m - bm);   // exp(-1e30)=0 on first tile
                l *= corr;
                #pragma unroll
                for (int i = 0; i < 64; ++i) acc[i] *= corr;
                m = bm;
            }

            const float p = __expf(score - m);       // masked lanes -> 0
            l += p;

            #pragma unroll
            for (int hq = 0; hq < 16; ++hq) {
                const float4 vv = *reinterpret_cast<const float4*>(&vs[lane][hq * 4]);
                acc[4*hq+0] += p * vv.x; acc[4*hq+1] += p * vv.y;
                acc[4*hq+2] += p * vv.z; acc[4*hq+3] += p * vv.w;
            }
        }
    }

    // Cross-lane reduction: sum partial out vectors and l over 64 lanes.
    #pragma unroll
    for (int off = 1; off < 64; off <<= 1) {
        l += __shfl_xor(l, off);
        #pragma unroll
        for (int i = 0; i < 64; ++i) acc[i] += __shfl_xor(acc[i], off);
    }

    // lane L stores h = L; pick acc[L] with static-index selects (no scratch).
    float myval = 0.f;
    #pragma unroll
    for (int i = 0; i < 64; ++i)
        if (lane == i) myval = acc[i];

    out[((size_t)b * T_ + t) * H_ + lane] = myval / l;
}

// ---------------------------------------------------------------------------
// Launch. Input order is setup_inputs() dict order: x, Wk, Wq, Wv (note Wk
// before Wq!). Workspace: q,k,v = 3 * B*T*H fp32 = 6 MB.
// ---------------------------------------------------------------------------
extern "C" void kernel_launch(void* const* d_in, const int* in_sizes, int n_in,
                              void* d_out, int out_size, void* d_ws, size_t ws_size,
                              hipStream_t stream)
{
    const float* x  = (const float*)d_in[0];
    const float* Wk = (const float*)d_in[1];
    const float* Wq = (const float*)d_in[2];
    const float* Wv = (const float*)d_in[3];
    float* out = (float*)d_out;

    float* qs = (float*)d_ws;                       // [B*T, H]
    float* ks = qs + (size_t)B_ * T_ * H_;          // [B*T, H]
    float* vsp = ks + (size_t)B_ * T_ * H_;         // [B*T, H]

    qkv_proj<<<dim3((B_ * T_) / 16), dim3(256), 0, stream>>>(x, Wq, Wk, Wv, qs, ks, vsp);
    attn_fwd<<<dim3(T_ / 4, B_), dim3(256), 0, stream>>>(qs, ks, vsp, out);
}

// Round 4
// 204.915 us; speedup vs baseline: 1.7263x; 1.7263x over previous
//
#include <hip/hip_runtime.h>
#include <hip/hip_bf16.h>

// Problem constants (B,T,C,H) = (4, 2048, 1024, 64)
#define B_ 4
#define T_ 2048
#define C_ 1024
#define H_ 64
#define M_ (B_ * T_)   // 8192 rows

typedef __attribute__((ext_vector_type(8))) short short8v;  // 8 bf16 = 4 VGPRs
typedef __attribute__((ext_vector_type(4))) float f32x4;

static __device__ __forceinline__ short bf16_bits(float f) {
    return __builtin_bit_cast(short, __float2bfloat16(f));
}

// ---------------------------------------------------------------------------
// Kernel 0: transpose+convert weights.  W[c][h] fp32 -> wt[m][h][c] bf16.
// 3*64*1024 elems; thread handles 4 consecutive c (8B store). Tiny, L2-bound.
// ---------------------------------------------------------------------------
__global__ __launch_bounds__(256) void w_transpose(
    const float* __restrict__ Wq,
    const float* __restrict__ Wk,
    const float* __restrict__ Wv,
    ushort* __restrict__ wt)
{
    const int idx = blockIdx.x * 256 + threadIdx.x;        // 0 .. 3*64*256-1
    const int m  = idx / (H_ * (C_ / 4));
    const int r  = idx % (H_ * (C_ / 4));
    const int h  = r / (C_ / 4);
    const int c0 = (r % (C_ / 4)) * 4;
    const float* W = (m == 0) ? Wq : (m == 1) ? Wk : Wv;
    ushort4 o;
    o.x = (ushort)bf16_bits(W[(size_t)(c0 + 0) * H_ + h]);
    o.y = (ushort)bf16_bits(W[(size_t)(c0 + 1) * H_ + h]);
    o.z = (ushort)bf16_bits(W[(size_t)(c0 + 2) * H_ + h]);
    o.w = (ushort)bf16_bits(W[(size_t)(c0 + 3) * H_ + h]);
    *reinterpret_cast<ushort4*>(&wt[((size_t)m * H_ + h) * C_ + c0]) = o;
}

// ---------------------------------------------------------------------------
// Kernel 1: fused QKV projection via bf16 MFMA.
// Grid = M/16 = 512 blocks, 256 thr (4 waves). Block owns 16 rows; wave w
// owns col-tile [16w, 16w+16) of H and all 3 matrices (A-frag reused 3x).
// Per K-step (32): A = x fp32 (2x float4, cvt->bf16), B = 3x short8 from
// bf16 W^T (16B contiguous, L2-resident).  mfma_f32_16x16x32_bf16:
//   A: row=lane&15, k=(lane>>4)*8+i   B: col=lane&15, k=(lane>>4)*8+i
//   D: col=lane&15, row=(lane>>4)*4+reg   [verified mapping]
// q pre-scaled by C^-0.5 = 1/32.
// ---------------------------------------------------------------------------
__global__ __launch_bounds__(256) void qkv_mfma(
    const float* __restrict__ x,
    const ushort* __restrict__ wt,     // [3][H][C] bf16 bits
    float* __restrict__ q_out,
    float* __restrict__ k_out,
    float* __restrict__ v_out)
{
    const int lane = threadIdx.x & 63;
    const int wid  = threadIdx.x >> 6;
    const int row0 = blockIdx.x * 16;
    const int col0 = wid * 16;
    const int l15  = lane & 15;        // A row / B col / D col
    const int kg   = lane >> 4;        // k-group 0..3

    const float*  xp = x  + (size_t)(row0 + l15) * C_ + kg * 8;
    const ushort* bq = wt + (size_t)(0 * H_ + col0 + l15) * C_ + kg * 8;
    const ushort* bk = bq + (size_t)H_ * C_;
    const ushort* bv = bk + (size_t)H_ * C_;

    f32x4 accq = {0.f, 0.f, 0.f, 0.f};
    f32x4 acck = {0.f, 0.f, 0.f, 0.f};
    f32x4 accv = {0.f, 0.f, 0.f, 0.f};

    #pragma unroll 4
    for (int kk = 0; kk < C_ / 32; ++kk) {
        const f32x4 a0 = *reinterpret_cast<const f32x4*>(xp + kk * 32);
        const f32x4 a1 = *reinterpret_cast<const f32x4*>(xp + kk * 32 + 4);
        short8v af;
        af[0] = bf16_bits(a0[0]); af[1] = bf16_bits(a0[1]);
        af[2] = bf16_bits(a0[2]); af[3] = bf16_bits(a0[3]);
        af[4] = bf16_bits(a1[0]); af[5] = bf16_bits(a1[1]);
        af[6] = bf16_bits(a1[2]); af[7] = bf16_bits(a1[3]);

        const short8v fq = *reinterpret_cast<const short8v*>(bq + kk * 32);
        const short8v fk = *reinterpret_cast<const short8v*>(bk + kk * 32);
        const short8v fv = *reinterpret_cast<const short8v*>(bv + kk * 32);

        accq = __builtin_amdgcn_mfma_f32_16x16x32_bf16(af, fq, accq, 0, 0, 0);
        acck = __builtin_amdgcn_mfma_f32_16x16x32_bf16(af, fk, acck, 0, 0, 0);
        accv = __builtin_amdgcn_mfma_f32_16x16x32_bf16(af, fv, accv, 0, 0, 0);
    }

    const float qscale = 0.03125f;  // 1024^-0.5
    #pragma unroll
    for (int j = 0; j < 4; ++j) {
        const size_t o = (size_t)(row0 + kg * 4 + j) * H_ + col0 + l15;
        q_out[o] = accq[j] * qscale;
        k_out[o] = acck[j];
        v_out[o] = accv[j];
    }
}

// ---------------------------------------------------------------------------
// Kernel 2: causal flash attention, fp32 (unchanged from round 0; ~95us,
// next round's target).
// ---------------------------------------------------------------------------
__global__ __launch_bounds__(256) void attn_fwd(
    const float* __restrict__ q,
    const float* __restrict__ k,
    const float* __restrict__ v,
    float* __restrict__ out)
{
    __shared__ __align__(16) float ks[64][68];
    __shared__ __align__(16) float vs[64][68];

    const int b    = blockIdx.y;
    const int wid  = threadIdx.x >> 6;
    const int lane = threadIdx.x & 63;
    const int t0   = blockIdx.x * 4;
    const int t    = t0 + wid;

    float qv[64];
    {
        const float4* qp = reinterpret_cast<const float4*>(&q[((size_t)b * T_ + t) * H_]);
        #pragma unroll
        for (int i = 0; i < 16; ++i) {
            const float4 tmp = qp[i];
            qv[4*i+0] = tmp.x; qv[4*i+1] = tmp.y;
            qv[4*i+2] = tmp.z; qv[4*i+3] = tmp.w;
        }
    }

    float acc[64];
    #pragma unroll
    for (int i = 0; i < 64; ++i) acc[i] = 0.f;
    float m = -1e30f;
    float l = 0.f;

    const int kbmax = (t0 + 3) >> 6;
    for (int kb = 0; kb <= kbmax; ++kb) {
        __syncthreads();
        #pragma unroll
        for (int rep = 0; rep < 4; ++rep) {
            const int idx = rep * 256 + threadIdx.x;
            const int s   = idx >> 4;
            const int hq  = idx & 15;
            const size_t g = ((size_t)b * T_ + (size_t)kb * 64 + s) * H_ + hq * 4;
            *reinterpret_cast<float4*>(&ks[s][hq * 4]) = *reinterpret_cast<const float4*>(&k[g]);
            *reinterpret_cast<float4*>(&vs[s][hq * 4]) = *reinterpret_cast<const float4*>(&v[g]);
        }
        __syncthreads();

        if (kb * 64 <= t) {
            const int s = kb * 64 + lane;
            float score = 0.f;
            #pragma unroll
            for (int hq = 0; hq < 16; ++hq) {
                const float4 kk = *reinterpret_cast<const float4*>(&ks[lane][hq * 4]);
                score += qv[4*hq+0] * kk.x + qv[4*hq+1] * kk.y
                       + qv[4*hq+2] * kk.z + qv[4*hq+3] * kk.w;
            }
            if (s > t) score = -1e30f;

            float bm = score;
            #pragma unroll
            for (int off = 32; off > 0; off >>= 1)
                bm = fmaxf(bm, __shfl_xor(bm, off));

            if (bm > m) {
                const float corr = __expf(m - bm);
                l *= corr;
                #pragma unroll
                for (int i = 0; i < 64; ++i) acc[i] *= corr;
                m = bm;
            }

            const float p = __expf(score - m);
            l += p;

            #pragma unroll
            for (int hq = 0; hq < 16; ++hq) {
                const float4 vv = *reinterpret_cast<const float4*>(&vs[lane][hq * 4]);
                acc[4*hq+0] += p * vv.x; acc[4*hq+1] += p * vv.y;
                acc[4*hq+2] += p * vv.z; acc[4*hq+3] += p * vv.w;
            }
        }
    }

    #pragma unroll
    for (int off = 1; off < 64; off <<= 1) {
        l += __shfl_xor(l, off);
        #pragma unroll
        for (int i = 0; i < 64; ++i) acc[i] += __shfl_xor(acc[i], off);
    }

    float myval = 0.f;
    #pragma unroll
    for (int i = 0; i < 64; ++i)
        if (lane == i) myval = acc[i];

    out[((size_t)b * T_ + t) * H_ + lane] = myval / l;
}

// ---------------------------------------------------------------------------
// Launch. Input order is setup_inputs() dict order: x, Wk, Wq, Wv.
// ws: q,k,v fp32 (3 * 8192*64 * 4B = 6 MB) + wt bf16 (3*64*1024*2 = 384 KB).
// ---------------------------------------------------------------------------
extern "C" void kernel_launch(void* const* d_in, const int* in_sizes, int n_in,
                              void* d_out, int out_size, void* d_ws, size_t ws_size,
                              hipStream_t stream)
{
    const float* x  = (const float*)d_in[0];
    const float* Wk = (const float*)d_in[1];
    const float* Wq = (const float*)d_in[2];
    const float* Wv = (const float*)d_in[3];
    float* out = (float*)d_out;

    float* qs  = (float*)d_ws;                      // [M, H]
    float* ksb = qs + (size_t)M_ * H_;              // [M, H]
    float* vsb = ksb + (size_t)M_ * H_;             // [M, H]
    ushort* wt = (ushort*)(vsb + (size_t)M_ * H_);  // [3][H][C] bf16

    w_transpose<<<dim3((3 * H_ * (C_ / 4)) / 256), dim3(256), 0, stream>>>(Wq, Wk, Wv, wt);
    qkv_mfma<<<dim3(M_ / 16), dim3(256), 0, stream>>>(x, wt, qs, ksb, vsb);
    attn_fwd<<<dim3(T_ / 4, B_), dim3(256), 0, stream>>>(qs, ksb, vsb, out);
}

// Round 5
// 136.986 us; speedup vs baseline: 2.5824x; 1.4959x over previous
//
#include <hip/hip_runtime.h>
#include <hip/hip_bf16.h>

// Problem constants (B,T,C,H) = (4, 2048, 1024, 64)
#define B_ 4
#define T_ 2048
#define C_ 1024
#define H_ 64
#define M_ (B_ * T_)   // 8192 rows

typedef __attribute__((ext_vector_type(8))) short short8v;  // 8 bf16 = 4 VGPRs
typedef __attribute__((ext_vector_type(4))) float f32x4;

static __device__ __forceinline__ short bf16_bits(float f) {
    return __builtin_bit_cast(short, __float2bfloat16(f));
}

// ---------------------------------------------------------------------------
// Kernel 0: transpose+convert weights.  W[c][h] fp32 -> wt[m][h][c] bf16.
// ---------------------------------------------------------------------------
__global__ __launch_bounds__(256) void w_transpose(
    const float* __restrict__ Wq,
    const float* __restrict__ Wk,
    const float* __restrict__ Wv,
    ushort* __restrict__ wt)
{
    const int idx = blockIdx.x * 256 + threadIdx.x;        // 0 .. 3*64*256-1
    const int m  = idx / (H_ * (C_ / 4));
    const int r  = idx % (H_ * (C_ / 4));
    const int h  = r / (C_ / 4);
    const int c0 = (r % (C_ / 4)) * 4;
    const float* W = (m == 0) ? Wq : (m == 1) ? Wk : Wv;
    ushort4 o;
    o.x = (ushort)bf16_bits(W[(size_t)(c0 + 0) * H_ + h]);
    o.y = (ushort)bf16_bits(W[(size_t)(c0 + 1) * H_ + h]);
    o.z = (ushort)bf16_bits(W[(size_t)(c0 + 2) * H_ + h]);
    o.w = (ushort)bf16_bits(W[(size_t)(c0 + 3) * H_ + h]);
    *reinterpret_cast<ushort4*>(&wt[((size_t)m * H_ + h) * C_ + c0]) = o;
}

// ---------------------------------------------------------------------------
// Kernel 1: fused QKV projection via bf16 MFMA.
// Outputs: qb [M][64] bf16 (pre-scaled by 1/32), kb [M][64] bf16,
//          vtp [B][64][T] bf16 (V transposed, for PV B-fragments).
// mfma_f32_16x16x32_bf16 mapping (verified):
//   A: row=lane&15, k=(lane>>4)*8+i   B: col=lane&15, k=(lane>>4)*8+i
//   D: col=lane&15, row=(lane>>4)*4+reg
// ---------------------------------------------------------------------------
__global__ __launch_bounds__(256) void qkv_mfma(
    const float* __restrict__ x,
    const ushort* __restrict__ wt,     // [3][H][C] bf16 bits
    ushort* __restrict__ qb,
    ushort* __restrict__ kb,
    ushort* __restrict__ vtp)
{
    const int lane = threadIdx.x & 63;
    const int wid  = threadIdx.x >> 6;
    const int row0 = blockIdx.x * 16;
    const int col0 = wid * 16;
    const int l15  = lane & 15;
    const int kg   = lane >> 4;

    const float*  xp = x  + (size_t)(row0 + l15) * C_ + kg * 8;
    const ushort* bq = wt + (size_t)(0 * H_ + col0 + l15) * C_ + kg * 8;
    const ushort* bk = bq + (size_t)H_ * C_;
    const ushort* bv = bk + (size_t)H_ * C_;

    f32x4 accq = {0.f, 0.f, 0.f, 0.f};
    f32x4 acck = {0.f, 0.f, 0.f, 0.f};
    f32x4 accv = {0.f, 0.f, 0.f, 0.f};

    #pragma unroll 4
    for (int kk = 0; kk < C_ / 32; ++kk) {
        const f32x4 a0 = *reinterpret_cast<const f32x4*>(xp + kk * 32);
        const f32x4 a1 = *reinterpret_cast<const f32x4*>(xp + kk * 32 + 4);
        short8v af;
        af[0] = bf16_bits(a0[0]); af[1] = bf16_bits(a0[1]);
        af[2] = bf16_bits(a0[2]); af[3] = bf16_bits(a0[3]);
        af[4] = bf16_bits(a1[0]); af[5] = bf16_bits(a1[1]);
        af[6] = bf16_bits(a1[2]); af[7] = bf16_bits(a1[3]);

        const short8v fq = *reinterpret_cast<const short8v*>(bq + kk * 32);
        const short8v fk = *reinterpret_cast<const short8v*>(bk + kk * 32);
        const short8v fv = *reinterpret_cast<const short8v*>(bv + kk * 32);

        accq = __builtin_amdgcn_mfma_f32_16x16x32_bf16(af, fq, accq, 0, 0, 0);
        acck = __builtin_amdgcn_mfma_f32_16x16x32_bf16(af, fk, acck, 0, 0, 0);
        accv = __builtin_amdgcn_mfma_f32_16x16x32_bf16(af, fv, accv, 0, 0, 0);
    }

    const float qscale = 0.03125f;  // 1024^-0.5
    #pragma unroll
    for (int j = 0; j < 4; ++j) {
        const int row = row0 + kg * 4 + j;               // global row 0..8191
        const size_t o = (size_t)row * H_ + col0 + l15;
        qb[o] = (ushort)bf16_bits(accq[j] * qscale);
        kb[o] = (ushort)bf16_bits(acck[j]);
        const int bb = row >> 11;                        // batch
        const int tt = row & (T_ - 1);                   // t within batch
        vtp[((size_t)bb * H_ + col0 + l15) * T_ + tt] = (ushort)bf16_bits(accv[j]);
    }
}

// ---------------------------------------------------------------------------
// Kernel 2: causal flash attention via bf16 MFMA.
// Grid (32, B) x 256 thr (4 waves). Wave w handles q-tile qt = 32*w + bx
// (16 q-rows), iterating k-tiles of 64 keys. No K/V LDS staging (L2-fit).
// Per k-tile: 8 QK MFMAs -> online softmax (rows live in lane-quarters,
// shfl_xor masks 1/2/4/8 stay in-quarter) -> P bf16 to per-wave LDS tile
// [16][68] -> 2 b128 reads give PA fragments -> 8 PV MFMAs (B from V^T).
// Only the last k-tile needs causal masking (16 rows < 64 keys).
// ---------------------------------------------------------------------------
__global__ __launch_bounds__(256) void attn_mfma(
    const ushort* __restrict__ qb,
    const ushort* __restrict__ kb,
    const ushort* __restrict__ vtp,
    float* __restrict__ out)
{
    __shared__ ushort p_lds[4][16][68];   // per-wave P tile, stride 68 bf16

    const int wid  = threadIdx.x >> 6;
    const int lane = threadIdx.x & 63;
    const int l15  = lane & 15;
    const int g    = lane >> 4;
    const int b    = blockIdx.y;
    const int qt   = wid * 32 + blockIdx.x;     // 0..127 (q-tile in batch)
    const int qrow0 = qt * 16;

    // Q fragments: rows qrow0+l15, k-steps h=0..31 and h=32..63
    const ushort* qp = qb + ((size_t)(b * T_ + qrow0 + l15)) * H_ + g * 8;
    const short8v qf0 = *reinterpret_cast<const short8v*>(qp);
    const short8v qf1 = *reinterpret_cast<const short8v*>(qp + 32);

    f32x4 accO[4];
    float m[4], l[4];
    #pragma unroll
    for (int r = 0; r < 4; ++r) {
        accO[r] = (f32x4){0.f, 0.f, 0.f, 0.f};
        m[r] = -1e30f; l[r] = 0.f;
    }

    const int lastkt = qrow0 >> 6;
    for (int kt = 0; kt <= lastkt; ++kt) {
        const int k0 = kt * 64;

        // ---- QK^T: S[16 q x 64 keys] as 4 col-tiles ----
        f32x4 s[4];
        #pragma unroll
        for (int c = 0; c < 4; ++c) s[c] = (f32x4){0.f, 0.f, 0.f, 0.f};
        const ushort* kbase = kb + ((size_t)(b * T_ + k0)) * H_;
        #pragma unroll
        for (int c = 0; c < 4; ++c) {
            const ushort* kp = kbase + (size_t)(c * 16 + l15) * H_ + g * 8;
            const short8v kf0 = *reinterpret_cast<const short8v*>(kp);
            const short8v kf1 = *reinterpret_cast<const short8v*>(kp + 32);
            s[c] = __builtin_amdgcn_mfma_f32_16x16x32_bf16(qf0, kf0, s[c], 0, 0, 0);
            s[c] = __builtin_amdgcn_mfma_f32_16x16x32_bf16(qf1, kf1, s[c], 0, 0, 0);
        }

        // ---- causal mask (only diagonal tile) ----
        if (kt == lastkt) {
            #pragma unroll
            for (int c = 0; c < 4; ++c) {
                const int key = k0 + c * 16 + l15;
                #pragma unroll
                for (int r = 0; r < 4; ++r) {
                    const int row = qrow0 + g * 4 + r;
                    if (key > row) s[c][r] = -1e30f;
                }
            }
        }

        // ---- online softmax: per-row (reg) reduce across 16 lanes ----
        float tm[4];
        #pragma unroll
        for (int r = 0; r < 4; ++r) {
            tm[r] = fmaxf(fmaxf(s[0][r], s[1][r]), fmaxf(s[2][r], s[3][r]));
            #pragma unroll
            for (int off = 1; off < 16; off <<= 1)
                tm[r] = fmaxf(tm[r], __shfl_xor(tm[r], off));
        }
        float corr[4];
        #pragma unroll
        for (int r = 0; r < 4; ++r) {
            const float mn = fmaxf(m[r], tm[r]);
            corr[r] = __expf(m[r] - mn);
            m[r] = mn;
        }
        #pragma unroll
        for (int ht = 0; ht < 4; ++ht)
            #pragma unroll
            for (int r = 0; r < 4; ++r)
                accO[ht][r] *= corr[r];

        float ts[4] = {0.f, 0.f, 0.f, 0.f};
        #pragma unroll
        for (int c = 0; c < 4; ++c) {
            #pragma unroll
            for (int r = 0; r < 4; ++r) {
                const float p = __expf(s[c][r] - m[r]);
                ts[r] += p;
                p_lds[wid][g * 4 + r][c * 16 + l15] = (ushort)bf16_bits(p);
            }
        }
        #pragma unroll
        for (int r = 0; r < 4; ++r) {
            #pragma unroll
            for (int off = 1; off < 16; off <<= 1)
                ts[r] += __shfl_xor(ts[r], off);
            l[r] = l[r] * corr[r] + ts[r];
        }

        // ---- PA fragments: P[l15][g*8 + 0..7 (+32)] ----
        const short8v pa0 = *reinterpret_cast<const short8v*>(&p_lds[wid][l15][g * 8]);
        const short8v pa1 = *reinterpret_cast<const short8v*>(&p_lds[wid][l15][32 + g * 8]);

        // ---- PV: O[16 q x 64 h] += P x V, B-frags from V^T [h][t] ----
        const ushort* vbase = vtp + (size_t)b * H_ * T_ + k0;
        #pragma unroll
        for (int ht = 0; ht < 4; ++ht) {
            const ushort* vp = vbase + (size_t)(ht * 16 + l15) * T_ + g * 8;
            const short8v vf0 = *reinterpret_cast<const short8v*>(vp);
            const short8v vf1 = *reinterpret_cast<const short8v*>(vp + 32);
            accO[ht] = __builtin_amdgcn_mfma_f32_16x16x32_bf16(pa0, vf0, accO[ht], 0, 0, 0);
            accO[ht] = __builtin_amdgcn_mfma_f32_16x16x32_bf16(pa1, vf1, accO[ht], 0, 0, 0);
        }
    }

    // ---- epilogue: out[row][h] = accO / l ----
    #pragma unroll
    for (int ht = 0; ht < 4; ++ht) {
        #pragma unroll
        for (int r = 0; r < 4; ++r) {
            const int row = qrow0 + g * 4 + r;
            out[((size_t)b * T_ + row) * H_ + ht * 16 + l15] = accO[ht][r] / l[r];
        }
    }
}

// ---------------------------------------------------------------------------
// Launch. Input order is setup_inputs() dict order: x, Wk, Wq, Wv.
// ws layout: qb 1MB | kb 1MB | vtp 1MB | wt 384KB  (bf16).
// ---------------------------------------------------------------------------
extern "C" void kernel_launch(void* const* d_in, const int* in_sizes, int n_in,
                              void* d_out, int out_size, void* d_ws, size_t ws_size,
                              hipStream_t stream)
{
    const float* x  = (const float*)d_in[0];
    const float* Wk = (const float*)d_in[1];
    const float* Wq = (const float*)d_in[2];
    const float* Wv = (const float*)d_in[3];
    float* out = (float*)d_out;

    ushort* qbp = (ushort*)d_ws;                    // [M][64]
    ushort* kbp = qbp + (size_t)M_ * H_;            // [M][64]
    ushort* vtp = kbp + (size_t)M_ * H_;            // [B][64][T]
    ushort* wt  = vtp + (size_t)B_ * H_ * T_;       // [3][64][1024]

    w_transpose<<<dim3((3 * H_ * (C_ / 4)) / 256), dim3(256), 0, stream>>>(Wq, Wk, Wv, wt);
    qkv_mfma<<<dim3(M_ / 16), dim3(256), 0, stream>>>(x, wt, qbp, kbp, vtp);
    attn_mfma<<<dim3(32, B_), dim3(256), 0, stream>>>(qbp, kbp, vtp, out);
}

// Round 6
// 88.791 us; speedup vs baseline: 3.9841x; 1.5428x over previous
//
#include <hip/hip_runtime.h>
#include <hip/hip_bf16.h>

// Problem constants (B,T,C,H) = (4, 2048, 1024, 64)
#define B_ 4
#define T_ 2048
#define C_ 1024
#define H_ 64
#define M_ (B_ * T_)   // 8192 rows

// Split-K attention geometry: q-tile = 16 rows, k-tile = 64 keys,
// chunk = 4 k-tiles = 256 keys. Units per batch:
//   nch(qt) = ceil((qt/4+1)/4) = qt/16 + 1;  sum over qt=0..127 = 576.
#define UPB 576
#define NUNITS (UPB * B_)   // 2304

typedef __attribute__((ext_vector_type(8))) short short8v;  // 8 bf16 = 4 VGPRs
typedef __attribute__((ext_vector_type(4))) float f32x4;

static __device__ __forceinline__ short bf16_bits(float f) {
    return __builtin_bit_cast(short, __float2bfloat16(f));
}

// ---------------------------------------------------------------------------
// Kernel 0: transpose+convert weights.  W[c][h] fp32 -> wt[m][h][c] bf16.
// ---------------------------------------------------------------------------
__global__ __launch_bounds__(256) void w_transpose(
    const float* __restrict__ Wq,
    const float* __restrict__ Wk,
    const float* __restrict__ Wv,
    ushort* __restrict__ wt)
{
    const int idx = blockIdx.x * 256 + threadIdx.x;        // 0 .. 3*64*256-1
    const int m  = idx / (H_ * (C_ / 4));
    const int r  = idx % (H_ * (C_ / 4));
    const int h  = r / (C_ / 4);
    const int c0 = (r % (C_ / 4)) * 4;
    const float* W = (m == 0) ? Wq : (m == 1) ? Wk : Wv;
    ushort4 o;
    o.x = (ushort)bf16_bits(W[(size_t)(c0 + 0) * H_ + h]);
    o.y = (ushort)bf16_bits(W[(size_t)(c0 + 1) * H_ + h]);
    o.z = (ushort)bf16_bits(W[(size_t)(c0 + 2) * H_ + h]);
    o.w = (ushort)bf16_bits(W[(size_t)(c0 + 3) * H_ + h]);
    *reinterpret_cast<ushort4*>(&wt[((size_t)m * H_ + h) * C_ + c0]) = o;
}

// ---------------------------------------------------------------------------
// Kernel 1: fused QKV projection via bf16 MFMA, LDS-staged coalesced epilogue.
// Outputs: qb [M][64] bf16 (pre-scaled 1/32), kb [M][64] bf16,
//          vtp [B][64][T] bf16 (V transposed).
// mfma_f32_16x16x32_bf16 mapping (verified):
//   A: row=lane&15, k=(lane>>4)*8+i   B: col=lane&15, k=(lane>>4)*8+i
//   D: col=lane&15, row=(lane>>4)*4+reg
// ---------------------------------------------------------------------------
__global__ __launch_bounds__(256) void qkv_mfma(
    const float* __restrict__ x,
    const ushort* __restrict__ wt,     // [3][H][C] bf16 bits
    ushort* __restrict__ qb,
    ushort* __restrict__ kb,
    ushort* __restrict__ vtp)
{
    __shared__ ushort q_s[16][72];     // [t][h], padded
    __shared__ ushort k_s[16][72];
    __shared__ ushort v_s[64][24];     // [h][t], padded (transposed V tile)

    const int lane = threadIdx.x & 63;
    const int wid  = threadIdx.x >> 6;
    const int row0 = blockIdx.x * 16;
    const int col0 = wid * 16;
    const int l15  = lane & 15;
    const int kg   = lane >> 4;

    const float*  xp = x  + (size_t)(row0 + l15) * C_ + kg * 8;
    const ushort* bq = wt + (size_t)(0 * H_ + col0 + l15) * C_ + kg * 8;
    const ushort* bk = bq + (size_t)H_ * C_;
    const ushort* bv = bk + (size_t)H_ * C_;

    f32x4 accq = {0.f, 0.f, 0.f, 0.f};
    f32x4 acck = {0.f, 0.f, 0.f, 0.f};
    f32x4 accv = {0.f, 0.f, 0.f, 0.f};

    #pragma unroll 4
    for (int kk = 0; kk < C_ / 32; ++kk) {
        const f32x4 a0 = *reinterpret_cast<const f32x4*>(xp + kk * 32);
        const f32x4 a1 = *reinterpret_cast<const f32x4*>(xp + kk * 32 + 4);
        short8v af;
        af[0] = bf16_bits(a0[0]); af[1] = bf16_bits(a0[1]);
        af[2] = bf16_bits(a0[2]); af[3] = bf16_bits(a0[3]);
        af[4] = bf16_bits(a1[0]); af[5] = bf16_bits(a1[1]);
        af[6] = bf16_bits(a1[2]); af[7] = bf16_bits(a1[3]);

        const short8v fq = *reinterpret_cast<const short8v*>(bq + kk * 32);
        const short8v fk = *reinterpret_cast<const short8v*>(bk + kk * 32);
        const short8v fv = *reinterpret_cast<const short8v*>(bv + kk * 32);

        accq = __builtin_amdgcn_mfma_f32_16x16x32_bf16(af, fq, accq, 0, 0, 0);
        acck = __builtin_amdgcn_mfma_f32_16x16x32_bf16(af, fk, acck, 0, 0, 0);
        accv = __builtin_amdgcn_mfma_f32_16x16x32_bf16(af, fv, accv, 0, 0, 0);
    }

    const float qscale = 0.03125f;  // 1024^-0.5
    #pragma unroll
    for (int j = 0; j < 4; ++j) {
        const int tr = kg * 4 + j;                 // row within 16-row tile
        q_s[tr][col0 + l15] = (ushort)bf16_bits(accq[j] * qscale);
        k_s[tr][col0 + l15] = (ushort)bf16_bits(acck[j]);
        v_s[col0 + l15][tr] = (ushort)bf16_bits(accv[j]);
    }
    __syncthreads();

    // q/k: 16 rows x 64 h; thread (row = tid>>4, seg = tid&15) -> ushort4.
    {
        const int row = threadIdx.x >> 4;
        const int seg = threadIdx.x & 15;
        const size_t o = (size_t)(row0 + row) * H_ + seg * 4;
        *reinterpret_cast<ushort4*>(&qb[o]) =
            *reinterpret_cast<const ushort4*>(&q_s[row][seg * 4]);
        *reinterpret_cast<ushort4*>(&kb[o]) =
            *reinterpret_cast<const ushort4*>(&k_s[row][seg * 4]);
    }
    // vtp: 64 h x 16 t; thread (h = tid>>2, seg = tid&3) -> ushort4.
    {
        const int h   = threadIdx.x >> 2;
        const int seg = threadIdx.x & 3;
        const int bb  = row0 >> 11;
        const int tt0 = row0 & (T_ - 1);
        *reinterpret_cast<ushort4*>(&vtp[((size_t)bb * H_ + h) * T_ + tt0 + seg * 4]) =
            *reinterpret_cast<const ushort4*>(&v_s[h][seg * 4]);
    }
}

// ---------------------------------------------------------------------------
// Kernel 2a: split-K causal flash attention partials via bf16 MFMA.
// Grid 576 blocks x 256 thr (4 waves); wave = one unit (b, qt, chunk).
// Unit decode: u within batch; a = qt>>4 found from 8a(a+1) <= u;
//   rr = (u - 8a(a+1)) / (a+1); chunk = remainder; qt = 16a + rr.
// Chunk covers k-tiles [chunk*4, min(chunk*4+4, qt/4+1)). Only the tile
// kt == qt>>2 contains the diagonal -> masked path; interior chunks take
// an unrolled mask-free 4-tile path. Partials (m,l,O) -> pML/pO.
// ---------------------------------------------------------------------------
__global__ __launch_bounds__(256) void attn_part(
    const ushort* __restrict__ qb,
    const ushort* __restrict__ kb,
    const ushort* __restrict__ vtp,
    float* __restrict__ pO,       // [NUNITS][16][64]
    float* __restrict__ pML)      // [NUNITS][32]  (m rows 0-15, l rows 16-31)
{
    __shared__ ushort p_lds[4][16][68];   // per-wave P tile

    const int wid  = threadIdx.x >> 6;
    const int lane = threadIdx.x & 63;
    const int l15  = lane & 15;
    const int g    = lane >> 4;

    const int unit = blockIdx.x * 4 + wid;
    const int b = unit / UPB;
    const int u = unit - b * UPB;
    int a = 0;
    #pragma unroll
    for (int t = 1; t < 8; ++t)
        if (u >= 8 * t * (t + 1)) a = t;
    const int u2    = u - 8 * a * (a + 1);
    const int rr    = u2 / (a + 1);
    const int chunk = u2 - rr * (a + 1);
    const int qt    = a * 16 + rr;

    const int qrow0   = qt * 16;
    const int diag_kt = qt >> 2;
    const int kt_lo   = chunk * 4;
    const int kt_hi   = min(kt_lo + 4, diag_kt + 1);   // exclusive

    const ushort* qp = qb + ((size_t)(b * T_ + qrow0 + l15)) * H_ + g * 8;
    const short8v qf0 = *reinterpret_cast<const short8v*>(qp);
    const short8v qf1 = *reinterpret_cast<const short8v*>(qp + 32);

    f32x4 accO[4];
    float m[4], l[4];
    #pragma unroll
    for (int r = 0; r < 4; ++r) {
        accO[r] = (f32x4){0.f, 0.f, 0.f, 0.f};
        m[r] = -1e30f; l[r] = 0.f;
    }

    auto do_tile = [&](int kt, bool mask) {
        const int k0 = kt * 64;

        // ---- QK^T: S[16 q x 64 keys] as 4 col-tiles ----
        f32x4 s[4];
        #pragma unroll
        for (int c = 0; c < 4; ++c) s[c] = (f32x4){0.f, 0.f, 0.f, 0.f};
        const ushort* kbase = kb + ((size_t)(b * T_ + k0)) * H_;
        #pragma unroll
        for (int c = 0; c < 4; ++c) {
            const ushort* kp = kbase + (size_t)(c * 16 + l15) * H_ + g * 8;
            const short8v kf0 = *reinterpret_cast<const short8v*>(kp);
            const short8v kf1 = *reinterpret_cast<const short8v*>(kp + 32);
            s[c] = __builtin_amdgcn_mfma_f32_16x16x32_bf16(qf0, kf0, s[c], 0, 0, 0);
            s[c] = __builtin_amdgcn_mfma_f32_16x16x32_bf16(qf1, kf1, s[c], 0, 0, 0);
        }

        // ---- V fragment loads (independent of softmax; issue early) ----
        const ushort* vbase = vtp + (size_t)b * H_ * T_ + k0;
        short8v vf0[4], vf1[4];
        #pragma unroll
        for (int ht = 0; ht < 4; ++ht) {
            const ushort* vp = vbase + (size_t)(ht * 16 + l15) * T_ + g * 8;
            vf0[ht] = *reinterpret_cast<const short8v*>(vp);
            vf1[ht] = *reinterpret_cast<const short8v*>(vp + 32);
        }

        // ---- causal mask (diagonal tile only) ----
        if (mask) {
            #pragma unroll
            for (int c = 0; c < 4; ++c) {
                const int key = k0 + c * 16 + l15;
                #pragma unroll
                for (int r = 0; r < 4; ++r) {
                    const int row = qrow0 + g * 4 + r;
                    if (key > row) s[c][r] = -1e30f;
                }
            }
        }

        // ---- online softmax: per-row reduce across 16 lanes ----
        float tm[4];
        #pragma unroll
        for (int r = 0; r < 4; ++r) {
            tm[r] = fmaxf(fmaxf(s[0][r], s[1][r]), fmaxf(s[2][r], s[3][r]));
            #pragma unroll
            for (int off = 1; off < 16; off <<= 1)
                tm[r] = fmaxf(tm[r], __shfl_xor(tm[r], off));
        }
        float corr[4];
        #pragma unroll
        for (int r = 0; r < 4; ++r) {
            const float mn = fmaxf(m[r], tm[r]);
            corr[r] = __expf(m[r] - mn);
            m[r] = mn;
        }
        #pragma unroll
        for (int ht = 0; ht < 4; ++ht)
            #pragma unroll
            for (int r = 0; r < 4; ++r)
                accO[ht][r] *= corr[r];

        float ts[4] = {0.f, 0.f, 0.f, 0.f};
        #pragma unroll
        for (int c = 0; c < 4; ++c) {
            #pragma unroll
            for (int r = 0; r < 4; ++r) {
                const float p = __expf(s[c][r] - m[r]);
                ts[r] += p;
                p_lds[wid][g * 4 + r][c * 16 + l15] = (ushort)bf16_bits(p);
            }
        }
        #pragma unroll
        for (int r = 0; r < 4; ++r) {
            #pragma unroll
            for (int off = 1; off < 16; off <<= 1)
                ts[r] += __shfl_xor(ts[r], off);
            l[r] = l[r] * corr[r] + ts[r];
        }

        // ---- PA fragments from per-wave LDS tile ----
        const short8v pa0 = *reinterpret_cast<const short8v*>(&p_lds[wid][l15][g * 8]);
        const short8v pa1 = *reinterpret_cast<const short8v*>(&p_lds[wid][l15][32 + g * 8]);

        // ---- PV: O += P x V ----
        #pragma unroll
        for (int ht = 0; ht < 4; ++ht) {
            accO[ht] = __builtin_amdgcn_mfma_f32_16x16x32_bf16(pa0, vf0[ht], accO[ht], 0, 0, 0);
            accO[ht] = __builtin_amdgcn_mfma_f32_16x16x32_bf16(pa1, vf1[ht], accO[ht], 0, 0, 0);
        }
    };

    if (kt_hi == kt_lo + 4 && kt_hi <= diag_kt) {
        // interior full chunk: straight-line, mask-free
        #pragma unroll
        for (int i = 0; i < 4; ++i) do_tile(kt_lo + i, false);
    } else {
        for (int kt = kt_lo; kt < kt_hi; ++kt) do_tile(kt, kt == diag_kt);
    }

    // ---- partial store ----
    float* po = pO + (size_t)unit * (16 * 64);
    #pragma unroll
    for (int ht = 0; ht < 4; ++ht)
        #pragma unroll
        for (int r = 0; r < 4; ++r)
            po[(g * 4 + r) * 64 + ht * 16 + l15] = accO[ht][r];
    if (l15 == 0) {
        #pragma unroll
        for (int r = 0; r < 4; ++r) {
            pML[(size_t)unit * 32 + (g * 4 + r)]      = m[r];
            pML[(size_t)unit * 32 + 16 + (g * 4 + r)] = l[r];
        }
    }
}

// ---------------------------------------------------------------------------
// Kernel 2b: merge partials.  Grid 512 blocks (b = bid>>7, qt = bid&127),
// 256 thr; thread handles (row stripe, h).  out = sum_u w_u*O_u / sum_u w_u*l_u.
// ---------------------------------------------------------------------------
__global__ __launch_bounds__(256) void attn_merge(
    const float* __restrict__ pO,
    const float* __restrict__ pML,
    float* __restrict__ out)
{
    const int b  = blockIdx.x >> 7;
    const int qt = blockIdx.x & 127;
    const int a  = qt >> 4;
    const int rr = qt & 15;
    const int base = b * UPB + 8 * a * (a + 1) + rr * (a + 1);
    const int nch  = a + 1;

    const int h  = threadIdx.x & 63;
    const int r0 = threadIdx.x >> 6;      // 0..3

    #pragma unroll
    for (int i = 0; i < 4; ++i) {
        const int row = r0 * 4 + i;       // 0..15
        float M = -1e30f;
        for (int u = 0; u < nch; ++u)
            M = fmaxf(M, pML[(size_t)(base + u) * 32 + row]);
        float O = 0.f, L = 0.f;
        for (int u = 0; u < nch; ++u) {
            const float w = __expf(pML[(size_t)(base + u) * 32 + row] - M);
            O += w * pO[(size_t)(base + u) * (16 * 64) + row * 64 + h];
            L += w * pML[(size_t)(base + u) * 32 + 16 + row];
        }
        out[((size_t)(b * T_ + qt * 16 + row)) * H_ + h] = O / L;
    }
}

// ---------------------------------------------------------------------------
// Launch. Input order is setup_inputs() dict order: x, Wk, Wq, Wv.
// ws: qb 1MB | kb 1MB | vtp 1MB | wt 384KB | pO 9.4MB | pML 294KB  (~13.1MB).
// ---------------------------------------------------------------------------
extern "C" void kernel_launch(void* const* d_in, const int* in_sizes, int n_in,
                              void* d_out, int out_size, void* d_ws, size_t ws_size,
                              hipStream_t stream)
{
    const float* x  = (const float*)d_in[0];
    const float* Wk = (const float*)d_in[1];
    const float* Wq = (const float*)d_in[2];
    const float* Wv = (const float*)d_in[3];
    float* out = (float*)d_out;

    ushort* qbp = (ushort*)d_ws;                    // [M][64]
    ushort* kbp = qbp + (size_t)M_ * H_;            // [M][64]
    ushort* vtp = kbp + (size_t)M_ * H_;            // [B][64][T]
    ushort* wt  = vtp + (size_t)B_ * H_ * T_;       // [3][64][1024]
    float*  pO  = (float*)(wt + (size_t)3 * H_ * C_);      // [NUNITS][16][64]
    float*  pML = pO + (size_t)NUNITS * 16 * 64;           // [NUNITS][32]

    w_transpose<<<dim3((3 * H_ * (C_ / 4)) / 256), dim3(256), 0, stream>>>(Wq, Wk, Wv, wt);
    qkv_mfma<<<dim3(M_ / 16), dim3(256), 0, stream>>>(x, wt, qbp, kbp, vtp);
    attn_part<<<dim3(NUNITS / 4), dim3(256), 0, stream>>>(qbp, kbp, vtp, pO, pML);
    attn_merge<<<dim3(128 * B_), dim3(256), 0, stream>>>(pO, pML, out);
}